// Round 12
// baseline (315.533 us; speedup 1.0000x reference)
//
#include <hip/hip_runtime.h>
#include <cstdint>
#include <cstddef>

using half8  = __attribute__((ext_vector_type(8))) _Float16;
using half4  = __attribute__((ext_vector_type(4))) _Float16;
using float4v = __attribute__((ext_vector_type(4))) float;

#define CD 1024
#define M2 (1024 * 1024)

// async global->LDS, 16B per lane, wave-uniform LDS base + lane*16 dest
#define GLD16(gp, lp)                                                          \
    __builtin_amdgcn_global_load_lds(                                          \
        (const __attribute__((address_space(1))) void*)(gp),                   \
        (__attribute__((address_space(3))) void*)(lp), 16, 0, 0)

// ---------------------------------------------------------------------------
// Weight prep: f32 -> f16, stack Wf/Wg/Wh into one (3C x C), stack biases.
// ---------------------------------------------------------------------------
__global__ void prep_weights(const float* __restrict__ Wf, const float* __restrict__ Wg,
                             const float* __restrict__ Wh, const float* __restrict__ Wc,
                             const float* __restrict__ bf, const float* __restrict__ bg,
                             const float* __restrict__ bh,
                             _Float16* __restrict__ Wfgh, _Float16* __restrict__ WcH,
                             float* __restrict__ bstack) {
    int idx = blockIdx.x * 256 + threadIdx.x;
    if (idx < 3 * M2) {
        const float* s = idx < M2 ? Wf : (idx < 2 * M2 ? Wg : Wh);
        int off = idx & (M2 - 1);
        Wfgh[idx] = (_Float16)s[off];
    } else if (idx < 4 * M2) {
        WcH[idx - 3 * M2] = (_Float16)Wc[idx - 3 * M2];
    } else if (idx < 4 * M2 + 3 * CD) {
        int j = idx - 4 * M2;
        const float* s = j < CD ? bf : (j < 2 * CD ? bg : bh);
        bstack[j] = s[j & (CD - 1)];
    }
}

// ---------------------------------------------------------------------------
// Tiled transpose: src[b0+z][k][n] (f32) -> dst[z][n][k] (f16)
// ---------------------------------------------------------------------------
__global__ void transpose_x(const float* __restrict__ x, _Float16* __restrict__ xT, int b0) {
    __shared__ float tile[32][33];
    int z = blockIdx.z;
    const float* xb = x + (size_t)(b0 + z) * M2;
    _Float16* xTb = xT + (size_t)z * M2;
    int n0 = blockIdx.x * 32, k0 = blockIdx.y * 32;
    int tx = threadIdx.x, ty = threadIdx.y;  // 32 x 8
#pragma unroll
    for (int i = 0; i < 4; i++)
        tile[ty + i * 8][tx] = xb[(size_t)(k0 + ty + i * 8) * CD + n0 + tx];
    __syncthreads();
#pragma unroll
    for (int i = 0; i < 4; i++)
        xTb[(size_t)(n0 + ty + i * 8) * CD + k0 + tx] = (_Float16)tile[tx][ty + i * 8];
}

// ---------------------------------------------------------------------------
// bch[o] = sum_c Wc[o][c] * bh[c]
// ---------------------------------------------------------------------------
__global__ __launch_bounds__(256) void gemv_bch(const float* __restrict__ Wc,
                                                const float* __restrict__ bh,
                                                float* __restrict__ bch) {
    int o = blockIdx.x * 4 + (threadIdx.x >> 6);
    int lane = threadIdx.x & 63;
    float s = 0.f;
    for (int c = lane; c < CD; c += 64) s += Wc[(size_t)o * CD + c] * bh[c];
#pragma unroll
    for (int off = 32; off > 0; off >>= 1) s += __shfl_xor(s, off);
    if (lane == 0) bch[o] = s;
}

// ---------------------------------------------------------------------------
// Split-K 1024^3 NT GEMM for Wch: z = K-slice [z*256,(z+1)*256), f32 partials.
// m97 structure, 128x128 tile, BK=32, 4 waves.
// ---------------------------------------------------------------------------
__global__ __launch_bounds__(256) void gemm128k(const _Float16* __restrict__ A,
                                                const _Float16* __restrict__ B,
                                                float* __restrict__ P) {
    __shared__ __align__(16) _Float16 As[128][32];
    __shared__ __align__(16) _Float16 Bs[128][32];
    int row0 = blockIdx.y * 128, col0 = blockIdx.x * 128;
    int koff = blockIdx.z * 256;
    int tid = threadIdx.x, lane = tid & 63, wave = tid >> 6;
    int wr = wave >> 1, wc = wave & 1;
    const int srow = lane >> 2;
    const int scol = (lane & 3) * 8;
    const size_t gA0 = (size_t)(row0 + wave * 16 + srow) * 1024 + koff + scol;
    const size_t gA1 = gA0 + (size_t)64 * 1024;
    const size_t gB0 = (size_t)(col0 + wave * 16 + srow) * 1024 + koff + scol;
    const size_t gB1 = gB0 + (size_t)64 * 1024;
    _Float16* ldsA0 = &As[wave * 16][0];
    _Float16* ldsA1 = &As[64 + wave * 16][0];
    _Float16* ldsB0 = &Bs[wave * 16][0];
    _Float16* ldsB1 = &Bs[64 + wave * 16][0];
    float4v acc[4][4] = {};
    const int kq = (lane >> 4) * 8, rl = lane & 15;
    for (int kt = 0; kt < 256; kt += 32) {
        GLD16(A + gA0 + kt, ldsA0);
        GLD16(A + gA1 + kt, ldsA1);
        GLD16(B + gB0 + kt, ldsB0);
        GLD16(B + gB1 + kt, ldsB1);
        __syncthreads();
        half8 af[4], bfr[4];
#pragma unroll
        for (int m = 0; m < 4; m++) af[m] = *(const half8*)(&As[wr * 64 + m * 16 + rl][kq]);
#pragma unroll
        for (int n = 0; n < 4; n++) bfr[n] = *(const half8*)(&Bs[wc * 64 + n * 16 + rl][kq]);
#pragma unroll
        for (int m = 0; m < 4; m++)
#pragma unroll
            for (int n = 0; n < 4; n++)
                acc[m][n] = __builtin_amdgcn_mfma_f32_16x16x32_f16(af[m], bfr[n], acc[m][n], 0, 0, 0);
        __syncthreads();
    }
    float* Pz = P + (size_t)blockIdx.z * M2;
#pragma unroll
    for (int m = 0; m < 4; m++)
#pragma unroll
        for (int r = 0; r < 4; r++) {
            int row = row0 + wr * 64 + m * 16 + ((lane >> 4) << 2) + r;
#pragma unroll
            for (int n = 0; n < 4; n++) {
                int col = col0 + wc * 64 + n * 16 + (lane & 15);
                Pz[(size_t)row * 1024 + col] = acc[m][n][r];
            }
        }
}

// Wch[i] = (f16)(P0[i]+P1[i]+P2[i]+P3[i])  — deterministic reduce.
__global__ __launch_bounds__(256) void reduce_wch(const float* __restrict__ P,
                                                  _Float16* __restrict__ Wch) {
    int i = (blockIdx.x * 256 + threadIdx.x) * 4;
    float4v s = *(const float4v*)(P + i);
#pragma unroll
    for (int z = 1; z < 4; z++) {
        float4v v = *(const float4v*)(P + (size_t)z * M2 + i);
        s[0] += v[0]; s[1] += v[1]; s[2] += v[2]; s[3] += v[3];
    }
    half4 o;
#pragma unroll
    for (int j = 0; j < 4; j++) o[j] = (_Float16)s[j];
    *(half4*)(Wch + i) = o;
}

// ---------------------------------------------------------------------------
// Row softmax over ST (f32) -> attnT (f16)
// ---------------------------------------------------------------------------
__global__ __launch_bounds__(256) void softmax_col(const float* __restrict__ ST,
                                                   _Float16* __restrict__ attnT) {
    int d = blockIdx.x, z = blockIdx.y;
    const float* row = ST + ((size_t)z * CD + d) * CD;
    _Float16* orow = attnT + ((size_t)z * CD + d) * CD;
    int t = threadIdx.x;
    float4v v = *(const float4v*)(row + t * 4);
    float mx = fmaxf(fmaxf(v[0], v[1]), fmaxf(v[2], v[3]));
#pragma unroll
    for (int o = 32; o > 0; o >>= 1) mx = fmaxf(mx, __shfl_xor(mx, o));
    __shared__ float redm[4], reds[4];
    int wave = t >> 6, lane = t & 63;
    if (lane == 0) redm[wave] = mx;
    __syncthreads();
    mx = fmaxf(fmaxf(redm[0], redm[1]), fmaxf(redm[2], redm[3]));
    float e[4];
    float s = 0.f;
#pragma unroll
    for (int i = 0; i < 4; i++) {
        e[i] = __expf(v[i] - mx);
        s += e[i];
    }
#pragma unroll
    for (int o = 32; o > 0; o >>= 1) s += __shfl_xor(s, o);
    if (lane == 0) reds[wave] = s;
    __syncthreads();
    s = reds[0] + reds[1] + reds[2] + reds[3];
    float inv = 1.0f / s;
    half4 ov;
#pragma unroll
    for (int i = 0; i < 4; i++) ov[i] = (_Float16)(e[i] * inv);
    *(half4*)(orow + t * 4) = ov;
}

// ---------------------------------------------------------------------------
// NT GEMM, 128x128 tile, BK=64, 2-buffer, ONE barrier/tile (r11 schedule),
// 2 BLOCKS/CU for cross-block overlap (m103/m114 mechanism).
// 4 waves (2Mx2N), per-wave 64x64 out (acc[4][4]), mfma 16x16x32 f16.
// LDS: As[2][128][64] + Bs[2][128][64] = 64 KiB -> 2 blocks/CU.
//
// Per tile t (buf=t&1; 8 gload_lds/tile/thread):
//   vmcnt(0) -> tile t landed; s_barrier -> published, buf^1 consumed
//   reads_h0 (8 b128) ; STAGE_A(t+1 -> buf^1) ; MFMA_h0 (16)
//   reads_h1 (8 b128) ; STAGE_B(t+1 -> buf^1) ; MFMA_h1 (16)
// While this block barriers/reads, the co-resident block MFMAs.
// K-order per acc unchanged -> bit-identical output.
// Swizzle (128B rows, involution c8 ^= row&7; verified 0 conflicts r10/r11):
//   stage: gload j covers rows [wv*32+j*8,+8), lane l -> row+(l>>3), LDS
//   c8=l&7 linear; global source c8=(l&7)^(l>>3).
//   read: col8(h) = ((lane>>4)+4h) ^ (rl&7); frag rows have row&7 == rl&7.
// ---------------------------------------------------------------------------
enum { EP_F16B = 0, EP_F32 = 1, EP_F16 = 2, EP_FIN = 3 };

#define STG_A(T, BUF)                                                          \
    GLD16(gA + (size_t)(T) * 64 + 0 * 8192, &As[BUF][wv * 32 + 0][0]);         \
    GLD16(gA + (size_t)(T) * 64 + 1 * 8192, &As[BUF][wv * 32 + 8][0]);         \
    GLD16(gA + (size_t)(T) * 64 + 2 * 8192, &As[BUF][wv * 32 + 16][0]);        \
    GLD16(gA + (size_t)(T) * 64 + 3 * 8192, &As[BUF][wv * 32 + 24][0]);
#define STG_B(T, BUF)                                                          \
    GLD16(gB + (size_t)(T) * 64 + 0 * 8192, &Bs[BUF][wv * 32 + 0][0]);         \
    GLD16(gB + (size_t)(T) * 64 + 1 * 8192, &Bs[BUF][wv * 32 + 8][0]);         \
    GLD16(gB + (size_t)(T) * 64 + 2 * 8192, &Bs[BUF][wv * 32 + 16][0]);        \
    GLD16(gB + (size_t)(T) * 64 + 3 * 8192, &Bs[BUF][wv * 32 + 24][0]);

#define READS(SET, BUF, COL)                                                   \
    _Pragma("unroll") for (int m = 0; m < 4; m++)                              \
        a##SET[m] = *(const half8*)&As[BUF][wr * 64 + m * 16 + rl][COL];       \
    _Pragma("unroll") for (int n = 0; n < 4; n++)                              \
        b##SET[n] = *(const half8*)&Bs[BUF][wc * 64 + n * 16 + rl][COL];

#define MFMA16(SET)                                                            \
    __builtin_amdgcn_s_setprio(1);                                             \
    _Pragma("unroll") for (int m = 0; m < 4; m++)                              \
        _Pragma("unroll") for (int n = 0; n < 4; n++)                          \
            acc[m][n] = __builtin_amdgcn_mfma_f32_16x16x32_f16(                \
                a##SET[m], b##SET[n], acc[m][n], 0, 0, 0);                     \
    __builtin_amdgcn_s_setprio(0);

#define TILE64(BUF, OBUF, DOSTAGE, STT)                                        \
    {                                                                          \
        asm volatile("s_waitcnt vmcnt(0)" ::: "memory");                       \
        __builtin_amdgcn_sched_barrier(0);                                     \
        __builtin_amdgcn_s_barrier();                                          \
        READS(0, BUF, c0)                                                      \
        if (DOSTAGE) { STG_A(STT, OBUF) }                                      \
        MFMA16(0)                                                              \
        READS(1, BUF, c1)                                                      \
        if (DOSTAGE) { STG_B(STT, OBUF) }                                      \
        MFMA16(1)                                                              \
    }

template <int EPI>
__global__ __launch_bounds__(256, 2) void gemm_nt(
    const _Float16* __restrict__ A, int64_t sA, const _Float16* __restrict__ B, int64_t sB,
    void* __restrict__ Cp, int64_t sC, const float* __restrict__ bias,
    const float* __restrict__ bc, const float* __restrict__ gamma,
    const float* __restrict__ beta, const float* __restrict__ rmean,
    const float* __restrict__ rvar, const float* __restrict__ xres) {
    __shared__ __align__(16) _Float16 As[2][128][64];
    __shared__ __align__(16) _Float16 Bs[2][128][64];
    int z = blockIdx.z;
    const _Float16* Ab = A + (size_t)z * sA;
    const _Float16* Bb = B + (size_t)z * sB;
    int row0 = blockIdx.y * 128, col0 = blockIdx.x * 128;
    int tid = threadIdx.x, lane = tid & 63, wv = tid >> 6;
    int wr = wv >> 1, wc = wv & 1;

    // Stage addressing: wave wv covers rows [wv*32, +32) via 4 gloads of 8
    // rows; lane l -> row +(l>>3), source col8 pre-swizzled (LDS linear).
    const _Float16* gA = Ab + (size_t)(row0 + wv * 32 + (lane >> 3)) * 1024 +
                         ((lane & 7) ^ (lane >> 3)) * 8;
    const _Float16* gB = Bb + (size_t)(col0 + wv * 32 + (lane >> 3)) * 1024 +
                         ((lane & 7) ^ (lane >> 3)) * 8;

    const int rl = lane & 15;
    const int q = lane >> 4;
    const int c0 = ((q) ^ (rl & 7)) * 8;      // k-half 0 read col (swizzled)
    const int c1 = ((q + 4) ^ (rl & 7)) * 8;  // k-half 1

    float4v acc[4][4] = {};
    half8 a0[4], b0[4], a1[4], b1[4];

    // Prologue: stage tile 0 into buf0.
    STG_A(0, 0) STG_B(0, 0)

    // 16 tiles of BK=64; tile t reads buf t&1, stages t+1 into buf (t+1)&1.
#pragma unroll 1
    for (int g = 0; g < 7; ++g) {  // t = 2g, 2g+1  (t=0..13, stages 1..14)
        int t = 2 * g;
        TILE64(0, 1, 1, t + 1)
        TILE64(1, 0, 1, t + 2)
    }
    TILE64(0, 1, 1, 15)  // t=14, stages tile 15
    TILE64(1, 0, 0, 0)   // t=15, nothing staged

    // Epilogue. C/D layout: col = lane&15, row = (lane>>4)*4 + reg  [m89]
#pragma unroll
    for (int m = 0; m < 4; m++) {
#pragma unroll
        for (int r = 0; r < 4; r++) {
            int row = row0 + wr * 64 + m * 16 + ((lane >> 4) << 2) + r;
            float add0 = 0.f, mu = 0.f, invs = 1.f, bet = 0.f;
            if constexpr (EPI == EP_F16B) add0 = bias[row];
            if constexpr (EPI == EP_FIN) {
                add0 = bc[row];
                mu = rmean[row];
                invs = gamma[row] * rsqrtf(rvar[row] + 1e-5f);
                bet = beta[row];
            }
#pragma unroll
            for (int n = 0; n < 4; n++) {
                int col = col0 + wc * 64 + n * 16 + (lane & 15);
                float v = acc[m][n][r];
                if constexpr (EPI == EP_F16B) {
                    ((_Float16*)Cp)[(size_t)z * sC + (size_t)row * 1024 + col] = (_Float16)(v + add0);
                } else if constexpr (EPI == EP_F32) {
                    ((float*)Cp)[(size_t)z * sC + (size_t)row * 1024 + col] = v;
                } else if constexpr (EPI == EP_F16) {
                    ((_Float16*)Cp)[(size_t)z * sC + (size_t)row * 1024 + col] = (_Float16)v;
                } else {
                    v += add0;
                    v = v >= 0.f ? v : 0.01f * v;
                    v = (v - mu) * invs + bet;
                    v += xres[(size_t)z * M2 + (size_t)row * 1024 + col];
                    ((float*)Cp)[(size_t)z * sC + (size_t)row * 1024 + col] = v;
                }
            }
        }
    }
}

// ---------------------------------------------------------------------------
extern "C" void kernel_launch(void* const* d_in, const int* in_sizes, int n_in,
                              void* d_out, int out_size, void* d_ws, size_t ws_size,
                              hipStream_t stream) {
    const float* x = (const float*)d_in[0];
    const float* Wf = (const float*)d_in[1];
    const float* bf = (const float*)d_in[2];
    const float* Wg = (const float*)d_in[3];
    const float* bg = (const float*)d_in[4];
    const float* Wh = (const float*)d_in[5];
    const float* bh = (const float*)d_in[6];
    const float* Wc = (const float*)d_in[7];
    const float* bc = (const float*)d_in[8];
    const float* gamma = (const float*)d_in[9];
    const float* beta = (const float*)d_in[10];
    const float* rmean = (const float*)d_in[11];
    const float* rvar = (const float*)d_in[12];

    // Fixed ws region: Wfgh f16 (6MB; slots F,G,CH) + WcH f16 (2MB) + bstack
    char* p = (char*)d_ws;
    _Float16* Wfgh = (_Float16*)p;
    p += (size_t)3 * M2 * 2;
    _Float16* WcH = (_Float16*)p;
    p += (size_t)M2 * 2;
    float* bstack = (float*)p;
    p += (size_t)3 * CD * 4;
    size_t fixed = (size_t)(p - (char*)d_ws);
    fixed = (fixed + 255) & ~(size_t)255;

    // Per-batch region: xT f16 (2MB, reused as attnT) + FGH f16 (6MB) +
    // ST f32 (4MB). 12 MiB per batch.
    size_t perB = (size_t)2 * M2 + (size_t)6 * M2 + (size_t)4 * M2;
    int nb = 16;
    while (nb > 1 && fixed + (size_t)nb * perB > ws_size) nb >>= 1;

    char* q = (char*)d_ws + fixed;

    {
        int total = 4 * M2 + 3 * CD;
        prep_weights<<<dim3((total + 255) / 256), dim3(256), 0, stream>>>(
            Wf, Wg, Wh, Wc, bf, bg, bh, Wfgh, WcH, bstack);
    }
    // Fold Wc into the h-projection:  Wch = Wc . Wh,  bch = Wc . bh.
    // Split-K (4 slices) + deterministic reduce; scratch in per-batch region
    // (WhT 2MB at q, partials 16MB after — all dead before the batch loop).
    {
        _Float16* WhT = (_Float16*)q;
        float* Pk = (float*)(q + (size_t)2 * M2);
        transpose_x<<<dim3(32, 32, 1), dim3(32, 8), 0, stream>>>(Wh, WhT, 0);
        gemv_bch<<<dim3(256), dim3(256), 0, stream>>>(Wc, bh, bstack + 2 * CD);
        gemm128k<<<dim3(8, 8, 4), dim3(256), 0, stream>>>(WcH, WhT, Pk);
        reduce_wch<<<dim3(M2 / 1024), dim3(256), 0, stream>>>(Pk, Wfgh + (size_t)2 * M2);
    }

    for (int b0 = 0; b0 < 16; b0 += nb) {
        _Float16* xT = (_Float16*)q;
        _Float16* FGH = (_Float16*)(q + (size_t)nb * 2 * M2);
        float* ST = (float*)(q + (size_t)nb * 8 * M2);
        _Float16* attnT = xT;  // xT dead after proj GEMM

        // xT[z][n][k] = x[b0+z][k][n]
        transpose_x<<<dim3(32, 32, nb), dim3(32, 8), 0, stream>>>(x, xT, b0);
        // FGH[z] (3072x1024) = [Wf;Wg;Wch] . xT[z]^T + [bf;bg;bch]
        gemm_nt<EP_F16B><<<dim3(8, 24, nb), dim3(256), 0, stream>>>(
            Wfgh, 0, xT, M2, FGH, (int64_t)3 * M2, bstack,
            nullptr, nullptr, nullptr, nullptr, nullptr, nullptr);
        // ST[z][d][c] = sum_n G[d][n] F[c][n]
        gemm_nt<EP_F32><<<dim3(8, 8, nb), dim3(256), 0, stream>>>(
            FGH + M2, (int64_t)3 * M2, FGH, (int64_t)3 * M2, ST, M2,
            nullptr, nullptr, nullptr, nullptr, nullptr, nullptr, nullptr);
        // attnT[z][d][c] = softmax over c of ST[z][d][:]
        softmax_col<<<dim3(1024, nb), dim3(256), 0, stream>>>(ST, attnT);
        // out[b][o][d] = BN(leaky(sum_n CH[o][n] attnT[d][n] + bc)) + x
        gemm_nt<EP_FIN><<<dim3(8, 8, nb), dim3(256), 0, stream>>>(
            FGH + (size_t)2 * M2, (int64_t)3 * M2, attnT, M2,
            (float*)d_out + (size_t)b0 * M2, M2,
            nullptr, bc, gamma, beta, rmean, rvar, x + (size_t)b0 * M2);
    }
}

// Round 13
// 268.427 us; speedup vs baseline: 1.1755x; 1.1755x over previous
//
#include <hip/hip_runtime.h>
#include <cstdint>
#include <cstddef>

using half8  = __attribute__((ext_vector_type(8))) _Float16;
using half4  = __attribute__((ext_vector_type(4))) _Float16;
using float4v = __attribute__((ext_vector_type(4))) float;

#define CD 1024
#define M2 (1024 * 1024)

// async global->LDS, 16B per lane, wave-uniform LDS base + lane*16 dest
#define GLD16(gp, lp)                                                          \
    __builtin_amdgcn_global_load_lds(                                          \
        (const __attribute__((address_space(1))) void*)(gp),                   \
        (__attribute__((address_space(3))) void*)(lp), 16, 0, 0)

// ---------------------------------------------------------------------------
// Weight prep: f32 -> f16, stack Wf/Wg/Wh into one (3C x C), stack biases.
// ---------------------------------------------------------------------------
__global__ void prep_weights(const float* __restrict__ Wf, const float* __restrict__ Wg,
                             const float* __restrict__ Wh, const float* __restrict__ Wc,
                             const float* __restrict__ bf, const float* __restrict__ bg,
                             const float* __restrict__ bh,
                             _Float16* __restrict__ Wfgh, _Float16* __restrict__ WcH,
                             float* __restrict__ bstack) {
    int idx = blockIdx.x * 256 + threadIdx.x;
    if (idx < 3 * M2) {
        const float* s = idx < M2 ? Wf : (idx < 2 * M2 ? Wg : Wh);
        int off = idx & (M2 - 1);
        Wfgh[idx] = (_Float16)s[off];
    } else if (idx < 4 * M2) {
        WcH[idx - 3 * M2] = (_Float16)Wc[idx - 3 * M2];
    } else if (idx < 4 * M2 + 3 * CD) {
        int j = idx - 4 * M2;
        const float* s = j < CD ? bf : (j < 2 * CD ? bg : bh);
        bstack[j] = s[j & (CD - 1)];
    }
}

// ---------------------------------------------------------------------------
// Tiled transpose: src[b0+z][k][n] (f32) -> dst[z][n][k] (f16)
// ---------------------------------------------------------------------------
__global__ void transpose_x(const float* __restrict__ x, _Float16* __restrict__ xT, int b0) {
    __shared__ float tile[32][33];
    int z = blockIdx.z;
    const float* xb = x + (size_t)(b0 + z) * M2;
    _Float16* xTb = xT + (size_t)z * M2;
    int n0 = blockIdx.x * 32, k0 = blockIdx.y * 32;
    int tx = threadIdx.x, ty = threadIdx.y;  // 32 x 8
#pragma unroll
    for (int i = 0; i < 4; i++)
        tile[ty + i * 8][tx] = xb[(size_t)(k0 + ty + i * 8) * CD + n0 + tx];
    __syncthreads();
#pragma unroll
    for (int i = 0; i < 4; i++)
        xTb[(size_t)(n0 + ty + i * 8) * CD + k0 + tx] = (_Float16)tile[tx][ty + i * 8];
}

// ---------------------------------------------------------------------------
// bch[o] = sum_c Wc[o][c] * bh[c]
// ---------------------------------------------------------------------------
__global__ __launch_bounds__(256) void gemv_bch(const float* __restrict__ Wc,
                                                const float* __restrict__ bh,
                                                float* __restrict__ bch) {
    int o = blockIdx.x * 4 + (threadIdx.x >> 6);
    int lane = threadIdx.x & 63;
    float s = 0.f;
    for (int c = lane; c < CD; c += 64) s += Wc[(size_t)o * CD + c] * bh[c];
#pragma unroll
    for (int off = 32; off > 0; off >>= 1) s += __shfl_xor(s, off);
    if (lane == 0) bch[o] = s;
}

// ---------------------------------------------------------------------------
// Split-K 1024^3 NT GEMM for Wch: z = K-slice [z*256,(z+1)*256), f32 partials.
// m97 structure, 128x128 tile, BK=32, 4 waves.
// ---------------------------------------------------------------------------
__global__ __launch_bounds__(256) void gemm128k(const _Float16* __restrict__ A,
                                                const _Float16* __restrict__ B,
                                                float* __restrict__ P) {
    __shared__ __align__(16) _Float16 As[128][32];
    __shared__ __align__(16) _Float16 Bs[128][32];
    int row0 = blockIdx.y * 128, col0 = blockIdx.x * 128;
    int koff = blockIdx.z * 256;
    int tid = threadIdx.x, lane = tid & 63, wave = tid >> 6;
    int wr = wave >> 1, wc = wave & 1;
    const int srow = lane >> 2;
    const int scol = (lane & 3) * 8;
    const size_t gA0 = (size_t)(row0 + wave * 16 + srow) * 1024 + koff + scol;
    const size_t gA1 = gA0 + (size_t)64 * 1024;
    const size_t gB0 = (size_t)(col0 + wave * 16 + srow) * 1024 + koff + scol;
    const size_t gB1 = gB0 + (size_t)64 * 1024;
    _Float16* ldsA0 = &As[wave * 16][0];
    _Float16* ldsA1 = &As[64 + wave * 16][0];
    _Float16* ldsB0 = &Bs[wave * 16][0];
    _Float16* ldsB1 = &Bs[64 + wave * 16][0];
    float4v acc[4][4] = {};
    const int kq = (lane >> 4) * 8, rl = lane & 15;
    for (int kt = 0; kt < 256; kt += 32) {
        GLD16(A + gA0 + kt, ldsA0);
        GLD16(A + gA1 + kt, ldsA1);
        GLD16(B + gB0 + kt, ldsB0);
        GLD16(B + gB1 + kt, ldsB1);
        __syncthreads();
        half8 af[4], bfr[4];
#pragma unroll
        for (int m = 0; m < 4; m++) af[m] = *(const half8*)(&As[wr * 64 + m * 16 + rl][kq]);
#pragma unroll
        for (int n = 0; n < 4; n++) bfr[n] = *(const half8*)(&Bs[wc * 64 + n * 16 + rl][kq]);
#pragma unroll
        for (int m = 0; m < 4; m++)
#pragma unroll
            for (int n = 0; n < 4; n++)
                acc[m][n] = __builtin_amdgcn_mfma_f32_16x16x32_f16(af[m], bfr[n], acc[m][n], 0, 0, 0);
        __syncthreads();
    }
    float* Pz = P + (size_t)blockIdx.z * M2;
#pragma unroll
    for (int m = 0; m < 4; m++)
#pragma unroll
        for (int r = 0; r < 4; r++) {
            int row = row0 + wr * 64 + m * 16 + ((lane >> 4) << 2) + r;
#pragma unroll
            for (int n = 0; n < 4; n++) {
                int col = col0 + wc * 64 + n * 16 + (lane & 15);
                Pz[(size_t)row * 1024 + col] = acc[m][n][r];
            }
        }
}

// Wch[i] = (f16)(P0[i]+P1[i]+P2[i]+P3[i])  — deterministic reduce.
__global__ __launch_bounds__(256) void reduce_wch(const float* __restrict__ P,
                                                  _Float16* __restrict__ Wch) {
    int i = (blockIdx.x * 256 + threadIdx.x) * 4;
    float4v s = *(const float4v*)(P + i);
#pragma unroll
    for (int z = 1; z < 4; z++) {
        float4v v = *(const float4v*)(P + (size_t)z * M2 + i);
        s[0] += v[0]; s[1] += v[1]; s[2] += v[2]; s[3] += v[3];
    }
    half4 o;
#pragma unroll
    for (int j = 0; j < 4; j++) o[j] = (_Float16)s[j];
    *(half4*)(Wch + i) = o;
}

// ---------------------------------------------------------------------------
// Row softmax over ST (f32) -> attnT (f16)
// ---------------------------------------------------------------------------
__global__ __launch_bounds__(256) void softmax_col(const float* __restrict__ ST,
                                                   _Float16* __restrict__ attnT) {
    int d = blockIdx.x, z = blockIdx.y;
    const float* row = ST + ((size_t)z * CD + d) * CD;
    _Float16* orow = attnT + ((size_t)z * CD + d) * CD;
    int t = threadIdx.x;
    float4v v = *(const float4v*)(row + t * 4);
    float mx = fmaxf(fmaxf(v[0], v[1]), fmaxf(v[2], v[3]));
#pragma unroll
    for (int o = 32; o > 0; o >>= 1) mx = fmaxf(mx, __shfl_xor(mx, o));
    __shared__ float redm[4], reds[4];
    int wave = t >> 6, lane = t & 63;
    if (lane == 0) redm[wave] = mx;
    __syncthreads();
    mx = fmaxf(fmaxf(redm[0], redm[1]), fmaxf(redm[2], redm[3]));
    float e[4];
    float s = 0.f;
#pragma unroll
    for (int i = 0; i < 4; i++) {
        e[i] = __expf(v[i] - mx);
        s += e[i];
    }
#pragma unroll
    for (int o = 32; o > 0; o >>= 1) s += __shfl_xor(s, o);
    if (lane == 0) reds[wave] = s;
    __syncthreads();
    s = reds[0] + reds[1] + reds[2] + reds[3];
    float inv = 1.0f / s;
    half4 ov;
#pragma unroll
    for (int i = 0; i < 4; i++) ov[i] = (_Float16)(e[i] * inv);
    *(half4*)(orow + t * 4) = ov;
}

// ---------------------------------------------------------------------------
// NT GEMM, 256x256, BK=64, 2-buffer, ONE barrier per 64-K tile (16 tiles).
// r11 structure (best measured: 922 TF) + T1 XCD-chunked block swizzle.
// 8 waves (2Mx4N), per-wave 128x64 out (acc[8][4]), mfma 16x16x32 f16.
// LDS: As[2][256][64] + Bs[2][256][64] = 128 KiB; 1 block/CU.
//
// 1D grid, nwg = gx*gy*gz (nwg % 8 == 0 at all call sites). Swizzle:
//   swz = (flat & 7) * (nwg/8) + (flat >> 3)   [bijective chunking]
//   bx = swz % gx (fastest), by = (swz/gx) % gy, z = swz/(gx*gy)
// Each XCD gets a contiguous (x,y,z) chunk -> shared A row-panels and ~2
// z-values of B (2 MB/z, XCD-L2-resident).
//
// Per tile t (buf=t&1; 8 gload_lds/tile/thread):
//   vmcnt(0) -> tile t landed; s_barrier -> published, buf^1 consumed
//   reads_h0 (12 b128) ; STAGE_A(t+1 -> buf^1) ; MFMA_h0 (32)
//   reads_h1 (12 b128) ; STAGE_B(t+1 -> buf^1) ; MFMA_h1 (32)
// K-order per acc = h0 then h1 -> bit-identical output.
// Swizzle (128B rows, involution c8 ^= row&7; verified 0 conflicts r10/r11):
//   stage: gload j covers rows [wv*32+j*8,+8), lane l -> row+(l>>3), LDS
//   c8=l&7 linear; global source c8=(l&7)^(l>>3).
//   read: col8(h) = ((lane>>4)+4h) ^ (rl&7); frag rows have row&7 == rl&7.
// ---------------------------------------------------------------------------
enum { EP_F16B = 0, EP_F32 = 1, EP_F16 = 2, EP_FIN = 3 };

#define STG_A(T, BUF)                                                          \
    GLD16(gA + (size_t)(T) * 64 + 0 * 8192, &As[BUF][wv * 32 + 0][0]);         \
    GLD16(gA + (size_t)(T) * 64 + 1 * 8192, &As[BUF][wv * 32 + 8][0]);         \
    GLD16(gA + (size_t)(T) * 64 + 2 * 8192, &As[BUF][wv * 32 + 16][0]);        \
    GLD16(gA + (size_t)(T) * 64 + 3 * 8192, &As[BUF][wv * 32 + 24][0]);
#define STG_B(T, BUF)                                                          \
    GLD16(gB + (size_t)(T) * 64 + 0 * 8192, &Bs[BUF][wv * 32 + 0][0]);         \
    GLD16(gB + (size_t)(T) * 64 + 1 * 8192, &Bs[BUF][wv * 32 + 8][0]);         \
    GLD16(gB + (size_t)(T) * 64 + 2 * 8192, &Bs[BUF][wv * 32 + 16][0]);        \
    GLD16(gB + (size_t)(T) * 64 + 3 * 8192, &Bs[BUF][wv * 32 + 24][0]);

#define READS(SET, BUF, COL)                                                   \
    _Pragma("unroll") for (int m = 0; m < 8; m++)                              \
        a##SET[m] = *(const half8*)&As[BUF][wr * 128 + m * 16 + rl][COL];      \
    _Pragma("unroll") for (int n = 0; n < 4; n++)                              \
        b##SET[n] = *(const half8*)&Bs[BUF][wc * 64 + n * 16 + rl][COL];

#define MFMA32(SET)                                                            \
    __builtin_amdgcn_s_setprio(1);                                             \
    _Pragma("unroll") for (int m = 0; m < 8; m++)                              \
        _Pragma("unroll") for (int n = 0; n < 4; n++)                          \
            acc[m][n] = __builtin_amdgcn_mfma_f32_16x16x32_f16(                \
                a##SET[m], b##SET[n], acc[m][n], 0, 0, 0);                     \
    __builtin_amdgcn_s_setprio(0);

#define TILE64(BUF, OBUF, DOSTAGE, STT)                                        \
    {                                                                          \
        asm volatile("s_waitcnt vmcnt(0)" ::: "memory");                       \
        __builtin_amdgcn_sched_barrier(0);                                     \
        __builtin_amdgcn_s_barrier();                                          \
        READS(0, BUF, c0)                                                      \
        if (DOSTAGE) { STG_A(STT, OBUF) }                                      \
        MFMA32(0)                                                              \
        READS(1, BUF, c1)                                                      \
        if (DOSTAGE) { STG_B(STT, OBUF) }                                      \
        MFMA32(1)                                                              \
    }

template <int EPI>
__global__ __launch_bounds__(512, 2) void gemm_nt(
    const _Float16* __restrict__ A, int64_t sA, const _Float16* __restrict__ B, int64_t sB,
    void* __restrict__ Cp, int64_t sC, int gx, int gy, const float* __restrict__ bias,
    const float* __restrict__ bc, const float* __restrict__ gamma,
    const float* __restrict__ beta, const float* __restrict__ rmean,
    const float* __restrict__ rvar, const float* __restrict__ xres) {
    __shared__ __align__(16) _Float16 As[2][256][64];
    __shared__ __align__(16) _Float16 Bs[2][256][64];

    // XCD-chunked bijective swizzle (nwg % 8 == 0 at all call sites).
    int flat = blockIdx.x;
    int cpx = gridDim.x >> 3;
    int swz = (flat & 7) * cpx + (flat >> 3);
    int bx = swz % gx;
    int rem = swz / gx;
    int by = rem % gy;
    int z = rem / gy;

    const _Float16* Ab = A + (size_t)z * sA;
    const _Float16* Bb = B + (size_t)z * sB;
    int row0 = by * 256, col0 = bx * 256;
    int tid = threadIdx.x, lane = tid & 63, wv = tid >> 6;
    int wr = wv >> 2, wc = wv & 3;

    // Stage addressing: wave wv covers rows [wv*32, +32) via 4 gloads of 8
    // rows; lane l -> row +(l>>3), source col8 pre-swizzled (LDS linear).
    const _Float16* gA = Ab + (size_t)(row0 + wv * 32 + (lane >> 3)) * 1024 +
                         ((lane & 7) ^ (lane >> 3)) * 8;
    const _Float16* gB = Bb + (size_t)(col0 + wv * 32 + (lane >> 3)) * 1024 +
                         ((lane & 7) ^ (lane >> 3)) * 8;

    const int rl = lane & 15;
    const int q = lane >> 4;
    const int c0 = ((q) ^ (rl & 7)) * 8;      // k-half 0 read col (swizzled)
    const int c1 = ((q + 4) ^ (rl & 7)) * 8;  // k-half 1

    float4v acc[8][4] = {};
    half8 a0[8], b0[4], a1[8], b1[4];

    // Prologue: stage tile 0 into buf0.
    STG_A(0, 0) STG_B(0, 0)

    // 16 tiles of BK=64; tile t reads buf t&1, stages t+1 into buf (t+1)&1.
#pragma unroll 1
    for (int g = 0; g < 7; ++g) {  // t = 2g, 2g+1  (t=0..13, stages 1..14)
        int t = 2 * g;
        TILE64(0, 1, 1, t + 1)
        TILE64(1, 0, 1, t + 2)
    }
    TILE64(0, 1, 1, 15)  // t=14, stages tile 15
    TILE64(1, 0, 0, 0)   // t=15, nothing staged

    // Epilogue. C/D layout: col = lane&15, row = (lane>>4)*4 + reg  [m89]
#pragma unroll
    for (int m = 0; m < 8; m++) {
#pragma unroll
        for (int r = 0; r < 4; r++) {
            int row = row0 + wr * 128 + m * 16 + ((lane >> 4) << 2) + r;
            float add0 = 0.f, mu = 0.f, invs = 1.f, bet = 0.f;
            if constexpr (EPI == EP_F16B) add0 = bias[row];
            if constexpr (EPI == EP_FIN) {
                add0 = bc[row];
                mu = rmean[row];
                invs = gamma[row] * rsqrtf(rvar[row] + 1e-5f);
                bet = beta[row];
            }
#pragma unroll
            for (int n = 0; n < 4; n++) {
                int col = col0 + wc * 64 + n * 16 + (lane & 15);
                float v = acc[m][n][r];
                if constexpr (EPI == EP_F16B) {
                    ((_Float16*)Cp)[(size_t)z * sC + (size_t)row * 1024 + col] = (_Float16)(v + add0);
                } else if constexpr (EPI == EP_F32) {
                    ((float*)Cp)[(size_t)z * sC + (size_t)row * 1024 + col] = v;
                } else if constexpr (EPI == EP_F16) {
                    ((_Float16*)Cp)[(size_t)z * sC + (size_t)row * 1024 + col] = (_Float16)v;
                } else {
                    v += add0;
                    v = v >= 0.f ? v : 0.01f * v;
                    v = (v - mu) * invs + bet;
                    v += xres[(size_t)z * M2 + (size_t)row * 1024 + col];
                    ((float*)Cp)[(size_t)z * sC + (size_t)row * 1024 + col] = v;
                }
            }
        }
    }
}

// ---------------------------------------------------------------------------
extern "C" void kernel_launch(void* const* d_in, const int* in_sizes, int n_in,
                              void* d_out, int out_size, void* d_ws, size_t ws_size,
                              hipStream_t stream) {
    const float* x = (const float*)d_in[0];
    const float* Wf = (const float*)d_in[1];
    const float* bf = (const float*)d_in[2];
    const float* Wg = (const float*)d_in[3];
    const float* bg = (const float*)d_in[4];
    const float* Wh = (const float*)d_in[5];
    const float* bh = (const float*)d_in[6];
    const float* Wc = (const float*)d_in[7];
    const float* bc = (const float*)d_in[8];
    const float* gamma = (const float*)d_in[9];
    const float* beta = (const float*)d_in[10];
    const float* rmean = (const float*)d_in[11];
    const float* rvar = (const float*)d_in[12];

    // Fixed ws region: Wfgh f16 (6MB; slots F,G,CH) + WcH f16 (2MB) + bstack
    char* p = (char*)d_ws;
    _Float16* Wfgh = (_Float16*)p;
    p += (size_t)3 * M2 * 2;
    _Float16* WcH = (_Float16*)p;
    p += (size_t)M2 * 2;
    float* bstack = (float*)p;
    p += (size_t)3 * CD * 4;
    size_t fixed = (size_t)(p - (char*)d_ws);
    fixed = (fixed + 255) & ~(size_t)255;

    // Per-batch region: xT f16 (2MB, reused as attnT) + FGH f16 (6MB) +
    // ST f32 (4MB). 12 MiB per batch.
    size_t perB = (size_t)2 * M2 + (size_t)6 * M2 + (size_t)4 * M2;
    int nb = 16;
    while (nb > 1 && fixed + (size_t)nb * perB > ws_size) nb >>= 1;

    char* q = (char*)d_ws + fixed;

    {
        int total = 4 * M2 + 3 * CD;
        prep_weights<<<dim3((total + 255) / 256), dim3(256), 0, stream>>>(
            Wf, Wg, Wh, Wc, bf, bg, bh, Wfgh, WcH, bstack);
    }
    // Fold Wc into the h-projection:  Wch = Wc . Wh,  bch = Wc . bh.
    // Split-K (4 slices) + deterministic reduce; scratch in per-batch region
    // (WhT 2MB at q, partials 16MB after — all dead before the batch loop).
    {
        _Float16* WhT = (_Float16*)q;
        float* Pk = (float*)(q + (size_t)2 * M2);
        transpose_x<<<dim3(32, 32, 1), dim3(32, 8), 0, stream>>>(Wh, WhT, 0);
        gemv_bch<<<dim3(256), dim3(256), 0, stream>>>(Wc, bh, bstack + 2 * CD);
        gemm128k<<<dim3(8, 8, 4), dim3(256), 0, stream>>>(WcH, WhT, Pk);
        reduce_wch<<<dim3(M2 / 1024), dim3(256), 0, stream>>>(Pk, Wfgh + (size_t)2 * M2);
    }

    for (int b0 = 0; b0 < 16; b0 += nb) {
        _Float16* xT = (_Float16*)q;
        _Float16* FGH = (_Float16*)(q + (size_t)nb * 2 * M2);
        float* ST = (float*)(q + (size_t)nb * 8 * M2);
        _Float16* attnT = xT;  // xT dead after proj GEMM

        // xT[z][n][k] = x[b0+z][k][n]
        transpose_x<<<dim3(32, 32, nb), dim3(32, 8), 0, stream>>>(x, xT, b0);
        // FGH[z] (3072x1024) = [Wf;Wg;Wch] . xT[z]^T + [bf;bg;bch]
        gemm_nt<EP_F16B><<<dim3(4 * 12 * nb), dim3(512), 0, stream>>>(
            Wfgh, 0, xT, M2, FGH, (int64_t)3 * M2, 4, 12, bstack,
            nullptr, nullptr, nullptr, nullptr, nullptr, nullptr);
        // ST[z][d][c] = sum_n G[d][n] F[c][n]
        gemm_nt<EP_F32><<<dim3(4 * 4 * nb), dim3(512), 0, stream>>>(
            FGH + M2, (int64_t)3 * M2, FGH, (int64_t)3 * M2, ST, M2, 4, 4,
            nullptr, nullptr, nullptr, nullptr, nullptr, nullptr, nullptr);
        // attnT[z][d][c] = softmax over c of ST[z][d][:]
        softmax_col<<<dim3(1024, nb), dim3(256), 0, stream>>>(ST, attnT);
        // out[b][o][d] = BN(leaky(sum_n CH[o][n] attnT[d][n] + bc)) + x
        gemm_nt<EP_FIN><<<dim3(4 * 4 * nb), dim3(512), 0, stream>>>(
            FGH + (size_t)2 * M2, (int64_t)3 * M2, attnT, M2,
            (float*)d_out + (size_t)b0 * M2, M2, 4, 4,
            nullptr, bc, gamma, beta, rmean, rvar, x + (size_t)b0 * M2);
    }
}